// Round 2
// baseline (620.610 us; speedup 1.0000x reference)
//
#include <hip/hip_runtime.h>
#include <stdint.h>

// ---------- types ----------
typedef int i32x4 __attribute__((ext_vector_type(4)));

#define PIDX(e) ((e) + ((e) >> 5))   // +1 dword pad per 32 to break LDS bank conflicts

// ---------- wave/block reductions (256 threads = 4 waves) ----------
__device__ __forceinline__ float wred_sum(float v) {
#pragma unroll
    for (int o = 32; o > 0; o >>= 1) v += __shfl_down(v, o, 64);
    return v;
}
__device__ __forceinline__ float wred_max(float v) {
#pragma unroll
    for (int o = 32; o > 0; o >>= 1) v = fmaxf(v, __shfl_down(v, o, 64));
    return v;
}
__device__ __forceinline__ float bred_sum(float v, float* sb, int tid) {
    v = wred_sum(v);
    __syncthreads();
    if ((tid & 63) == 0) sb[tid >> 6] = v;
    __syncthreads();
    return sb[0] + sb[1] + sb[2] + sb[3];
}
__device__ __forceinline__ float bred_max(float v, float* sb, int tid) {
    v = wred_max(v);
    __syncthreads();
    if ((tid & 63) == 0) sb[tid >> 6] = v;
    __syncthreads();
    return fmaxf(fmaxf(sb[0], sb[1]), fmaxf(sb[2], sb[3]));
}

__device__ __forceinline__ int pack4(int a, int b, int c, int d) {
    return (a & 0xff) | ((b & 0xff) << 8) | ((c & 0xff) << 16) | ((d & 0xff) << 24);
}

// ---------- 16-point in-register FWHT ----------
__device__ __forceinline__ void fwht16(float v[16]) {
#pragma unroll
    for (int h = 1; h < 16; h <<= 1) {
#pragma unroll
        for (int i = 0; i < 16; ++i) {
            if ((i & h) == 0) {
                float a = v[i], b = v[i + h];
                v[i] = a + b;
                v[i + h] = a - b;
            }
        }
    }
}

// FWHT of 4096 floats living in padded LDS f[PIDX(e)], 256 threads.
// 3 phases of radix-16 (bits 0-3, 4-7, 8-11). Caller fills LDS first.
__device__ void fwht4096(float* f, int t) {
    __syncthreads();
    float v[16];
    {   // bits 0-3: e = t*16 + i
        int base = t << 4;
#pragma unroll
        for (int i = 0; i < 16; ++i) v[i] = f[PIDX(base + i)];
        fwht16(v);
#pragma unroll
        for (int i = 0; i < 16; ++i) f[PIDX(base + i)] = v[i];
    }
    __syncthreads();
    {   // bits 4-7: e = (t>>4)*256 + i*16 + (t&15)
        int base = ((t >> 4) << 8) | (t & 15);
#pragma unroll
        for (int i = 0; i < 16; ++i) v[i] = f[PIDX(base + (i << 4))];
        fwht16(v);
#pragma unroll
        for (int i = 0; i < 16; ++i) f[PIDX(base + (i << 4))] = v[i];
    }
    __syncthreads();
    {   // bits 8-11: e = i*256 + t
        int base = t;
#pragma unroll
        for (int i = 0; i < 16; ++i) v[i] = f[PIDX(base + (i << 8))];
        fwht16(v);
#pragma unroll
        for (int i = 0; i < 16; ++i) f[PIDX(base + (i << 8))] = v[i];
    }
    __syncthreads();
}

// ---------- K1a: partial sums of |w| ----------
__global__ __launch_bounds__(256) void k_wabs(const float* __restrict__ w,
                                              float* __restrict__ partials) {
    __shared__ float sb[4];
    const int t = threadIdx.x;
    const int b = blockIdx.x;
    float acc = 0.0f;
#pragma unroll
    for (int i = 0; i < 8; ++i) {
        float4 f = *(const float4*)(w + (size_t)(b * 2048 + i * 256 + t) * 4);
        acc += fabsf(f.x) + fabsf(f.y) + fabsf(f.z) + fabsf(f.w);
    }
    float tot = bred_sum(acc, sb, t);
    if (t == 0) partials[b] = tot;
}

// ---------- K1a2: final scale = mean|w| ----------
__global__ __launch_bounds__(256) void k_wscale(const float* __restrict__ partials,
                                                float* __restrict__ sfinal) {
    __shared__ float sb[4];
    const int t = threadIdx.x;
    float a = 0.0f;
#pragma unroll
    for (int i = 0; i < 8; ++i) a += partials[t + i * 256];
    float tot = bred_sum(a, sb, t);
    if (t == 0) sfinal[0] = tot * (1.0f / 16777216.0f);
}

// ---------- K1b: ternary quantize weight row, FWHT, split into hi/lo i8 ----------
__global__ __launch_bounds__(256) void k_wprep(const float* __restrict__ w,
                                               const float* __restrict__ sfinal,
                                               int8_t* __restrict__ hi,
                                               int8_t* __restrict__ lo) {
    __shared__ float f[4224];
    const int t = threadIdx.x;
    const int o = blockIdx.x;
    const float thr = 0.5f * sfinal[0];
    const float* wr = w + (size_t)o * 4096;
#pragma unroll
    for (int j = 0; j < 4; ++j) {
        float4 g = *(const float4*)(wr + j * 1024 + t * 4);
        int e = j * 1024 + t * 4;
        f[PIDX(e + 0)] = (g.x > thr) ? 1.0f : ((g.x < -thr) ? -1.0f : 0.0f);
        f[PIDX(e + 1)] = (g.y > thr) ? 1.0f : ((g.y < -thr) ? -1.0f : 0.0f);
        f[PIDX(e + 2)] = (g.z > thr) ? 1.0f : ((g.z < -thr) ? -1.0f : 0.0f);
        f[PIDX(e + 3)] = (g.w > thr) ? 1.0f : ((g.w < -thr) ? -1.0f : 0.0f);
    }
    fwht4096(f, t);
    int* hi32 = (int*)hi;
    int* lo32 = (int*)lo;
#pragma unroll
    for (int j = 0; j < 4; ++j) {
        int e = j * 1024 + t * 4;
        int l4[4], h4[4];
#pragma unroll
        for (int q = 0; q < 4; ++q) {
            int v = __float2int_rn(f[PIDX(e + q)]);       // exact integer in [-4096,4096]
            int lv = ((v + 128) & 255) - 128;             // [-128,127]
            int hv = (v - lv) >> 8;                       // [-16,16]
            l4[q] = lv; h4[q] = hv;
        }
        lo32[(size_t)o * 1024 + j * 256 + t] = pack4(l4[0], l4[1], l4[2], l4[3]);
        hi32[(size_t)o * 1024 + j * 256 + t] = pack4(h4[0], h4[1], h4[2], h4[3]);
    }
}

// ---------- K2: fused LayerNorm + absmax + int4 quantize -> i8 ----------
__global__ __launch_bounds__(256) void k_lnq(const float* __restrict__ x,
                                             const float* __restrict__ gamma,
                                             const float* __restrict__ beta,
                                             int8_t* __restrict__ xq) {
    __shared__ float sb[4];
    const int t = threadIdx.x;
    const size_t row = blockIdx.x;
    const float* xr = x + row * 4096;
    float v[16];
#pragma unroll
    for (int j = 0; j < 4; ++j) {
        float4 g = *(const float4*)(xr + j * 1024 + t * 4);
        v[j * 4 + 0] = g.x; v[j * 4 + 1] = g.y; v[j * 4 + 2] = g.z; v[j * 4 + 3] = g.w;
    }
    float s = 0.0f;
#pragma unroll
    for (int i = 0; i < 16; ++i) s += v[i];
    const float mu = bred_sum(s, sb, t) * (1.0f / 4096.0f);
    float sq = 0.0f;
#pragma unroll
    for (int i = 0; i < 16; ++i) { float d = v[i] - mu; sq += d * d; }
    const float var = bred_sum(sq, sb, t) * (1.0f / 4096.0f);
    const float rstd = rsqrtf(var + 1e-5f);
#pragma unroll
    for (int j = 0; j < 4; ++j) {
        float4 g = *(const float4*)(gamma + j * 1024 + t * 4);
        float4 b = *(const float4*)(beta + j * 1024 + t * 4);
        v[j * 4 + 0] = (v[j * 4 + 0] - mu) * rstd * g.x + b.x;
        v[j * 4 + 1] = (v[j * 4 + 1] - mu) * rstd * g.y + b.y;
        v[j * 4 + 2] = (v[j * 4 + 2] - mu) * rstd * g.z + b.z;
        v[j * 4 + 3] = (v[j * 4 + 3] - mu) * rstd * g.w + b.w;
    }
    float am = 0.0f;
#pragma unroll
    for (int i = 0; i < 16; ++i) am = fmaxf(am, fabsf(v[i]));
    am = bred_max(am, sb, t);
    const float scale = fminf(fmaxf(am, 1e-6f), 1e6f);
    const float sf = fminf(fmaxf(7.0f / scale, 1e-6f), 1e6f);
    int* xq32 = (int*)xq;
#pragma unroll
    for (int j = 0; j < 4; ++j) {
        int q4[4];
#pragma unroll
        for (int q = 0; q < 4; ++q) {
            float qq = rintf(v[j * 4 + q] * sf);           // round-half-even, matches jnp.round
            qq = fminf(fmaxf(qq, -7.0f), 7.0f);
            q4[q] = (int)qq;
        }
        xq32[row * 1024 + j * 256 + t] = pack4(q4[0], q4[1], q4[2], q4[3]);
    }
}

// ---------- async global -> LDS, 16B per lane ----------
__device__ __forceinline__ void gl_lds16(const void* g, void* l) {
    __builtin_amdgcn_global_load_lds(
        (const __attribute__((address_space(1))) void*)g,
        (__attribute__((address_space(3))) void*)l, 16, 0, 0);
}

// ---------- K3: dual i8 GEMM  out[r,o] = s * sum_d xq[r,d] * (256*hi[o,d]+lo[o,d]) ----------
// Tiles: BM=128, BN=128, BK=64. 4 waves, each owns a 64x64 sub-tile (4x4 frags of 16x16).
//
// LDS chunk swizzle (T2, rule #21): tile row R, 16B-chunk c is stored at chunk
// position p = c ^ phi(R), phi(R) = (R>>1)&3. Since global_load_lds writes
// lane-linear (dest = base + lane*16), the permutation is applied to the
// per-lane GLOBAL source address; reads apply the same XOR. phi is invariant
// under R += 16/32/64, so one per-lane offset covers all staging calls and all
// m-subtiles. Result: every bank exactly 2-way (free, m136) instead of 8-way.
__global__ __launch_bounds__(256, 2) void k_gemm(const int8_t* __restrict__ xq,
                                                 const int8_t* __restrict__ hi,
                                                 const int8_t* __restrict__ lo,
                                                 const float* __restrict__ sfinal,
                                                 float* __restrict__ out) {
    __shared__ __align__(16) int8_t sA[128 * 64];
    __shared__ __align__(16) int8_t sH[128 * 64];
    __shared__ __align__(16) int8_t sL[128 * 64];
    const int tid = threadIdx.x;
    const int lane = tid & 63, wid = tid >> 6;
    const int wr = wid >> 1, wc = wid & 1;
    // XCD-aware swizzle: nwg = 2048, divisible by 8 -> bijective
    const int bid = blockIdx.x;
    const int wg = (bid & 7) * 256 + (bid >> 3);
    const int bm = wg & 63, bn = wg >> 6;       // 64 row-blocks x 32 col-blocks
    const int row0 = bm * 128, col0 = bn * 128;

    // staging: wave wid covers tile rows [wid*32, wid*32+32), two 16-row chunks
    const int srow = lane >> 2;                       // row within 16-row chunk
    const int csw = ((lane & 3) ^ ((srow >> 1) & 3)) * 16;   // swizzled global chunk
    const int8_t* gA = xq + (size_t)(row0 + wid * 32 + srow) * 4096 + csw;
    const int8_t* gH = hi + (size_t)(col0 + wid * 32 + srow) * 4096 + csw;
    const int8_t* gL = lo + (size_t)(col0 + wid * 32 + srow) * 4096 + csw;
    int8_t* lA = sA + wid * 2048 + lane * 16;         // lane-linear dest (HW requirement)
    int8_t* lH = sH + wid * 2048 + lane * 16;
    int8_t* lL = sL + wid * 2048 + lane * 16;

    // fragment addresses: row = lane&15, k-chunk = lane>>4, swizzled position
    const int frow = lane & 15;
    const int pr = ((lane >> 4) ^ ((frow >> 1) & 3)) * 16;
    const int aoff = (wr * 64 + frow) * 64 + pr;
    const int boff = (wc * 64 + frow) * 64 + pr;

    i32x4 accL[4][4] = {};
    i32x4 accH[4][4] = {};

    for (int kt = 0; kt < 4096; kt += 64) {
        gl_lds16(gA + kt, lA);
        gl_lds16(gA + kt + 16 * 4096, lA + 1024);
        gl_lds16(gH + kt, lH);
        gl_lds16(gH + kt + 16 * 4096, lH + 1024);
        gl_lds16(gL + kt, lL);
        gl_lds16(gL + kt + 16 * 4096, lL + 1024);
        __syncthreads();

        i32x4 a[4], bh[4], bl[4];
#pragma unroll
        for (int m = 0; m < 4; ++m) a[m] = *(const i32x4*)(sA + aoff + m * 1024);
#pragma unroll
        for (int n = 0; n < 4; ++n) {
            bh[n] = *(const i32x4*)(sH + boff + n * 1024);
            bl[n] = *(const i32x4*)(sL + boff + n * 1024);
        }
#pragma unroll
        for (int m = 0; m < 4; ++m)
#pragma unroll
            for (int n = 0; n < 4; ++n) {
                accL[m][n] = __builtin_amdgcn_mfma_i32_16x16x64_i8(a[m], bl[n], accL[m][n], 0, 0, 0);
                accH[m][n] = __builtin_amdgcn_mfma_i32_16x16x64_i8(a[m], bh[n], accH[m][n], 0, 0, 0);
            }
        __syncthreads();
    }

    const float s = sfinal[0];
    const int orow0 = row0 + wr * 64 + (lane >> 4) * 4;
    const int ocol0 = col0 + wc * 64 + frow;
#pragma unroll
    for (int m = 0; m < 4; ++m)
#pragma unroll
        for (int n = 0; n < 4; ++n)
#pragma unroll
            for (int r = 0; r < 4; ++r) {
                int val = accL[m][n][r] + (accH[m][n][r] << 8);   // exact i32
                out[(size_t)(orow0 + m * 16 + r) * 4096 + (ocol0 + n * 16)] = s * (float)val;
            }
}

// ---------- K4: in-place FWHT along output dim ----------
__global__ __launch_bounds__(256) void k_fwht_out(float* __restrict__ out) {
    __shared__ float f[4224];
    const int t = threadIdx.x;
    float* row = out + (size_t)blockIdx.x * 4096;
#pragma unroll
    for (int j = 0; j < 4; ++j) {
        float4 g = *(const float4*)(row + j * 1024 + t * 4);
        int e = j * 1024 + t * 4;
        f[PIDX(e + 0)] = g.x; f[PIDX(e + 1)] = g.y;
        f[PIDX(e + 2)] = g.z; f[PIDX(e + 3)] = g.w;
    }
    fwht4096(f, t);
#pragma unroll
    for (int j = 0; j < 4; ++j) {
        int e = j * 1024 + t * 4;
        float4 g;
        g.x = f[PIDX(e + 0)]; g.y = f[PIDX(e + 1)];
        g.z = f[PIDX(e + 2)]; g.w = f[PIDX(e + 3)];
        *(float4*)(row + e) = g;
    }
}

// ---------- launch ----------
extern "C" void kernel_launch(void* const* d_in, const int* in_sizes, int n_in,
                              void* d_out, int out_size, void* d_ws, size_t ws_size,
                              hipStream_t stream) {
    const float* x     = (const float*)d_in[0];
    const float* gamma = (const float*)d_in[1];
    const float* beta  = (const float*)d_in[2];
    const float* w     = (const float*)d_in[3];
    float* out = (float*)d_out;

    char* ws = (char*)d_ws;
    float* sfinal   = (float*)ws;                       // 4 B
    float* partials = (float*)(ws + 256);               // 2048 floats
    int8_t* xq  = (int8_t*)(ws + 16384);                // 8192*4096 = 33.5 MB
    int8_t* whi = (int8_t*)(ws + 16384 + 33554432);     // 16.7 MB
    int8_t* wlo = (int8_t*)(ws + 16384 + 33554432 + 16777216); // 16.7 MB

    k_wabs  <<<2048, 256, 0, stream>>>(w, partials);
    k_wscale<<<   1, 256, 0, stream>>>(partials, sfinal);
    k_wprep <<<4096, 256, 0, stream>>>(w, sfinal, whi, wlo);
    k_lnq   <<<8192, 256, 0, stream>>>(x, gamma, beta, xq);
    k_gemm  <<<2048, 256, 0, stream>>>(xq, whi, wlo, sfinal, out);
    k_fwht_out<<<8192, 256, 0, stream>>>(out);
}